// Round 1
// baseline (241.143 us; speedup 1.0000x reference)
//
#include <hip/hip_runtime.h>
#include <hip/hip_bf16.h>

#define MARGIN_F 0.25f

// Problem constants (fixed by setup_inputs).
#define B_ANCH 2048
#define P_POS  2048
#define N_NEG  32768   // 2048 * 16
#define DDIM   128

typedef __attribute__((ext_vector_type(8))) short bf16x8;   // 8 bf16 = 4 VGPRs
typedef __attribute__((ext_vector_type(4))) float f32x4;

__device__ __forceinline__ short f2bf(float x) {
    __hip_bfloat16 h = __float2bfloat16(x);
    return *reinterpret_cast<short*>(&h);
}

// ---------------------------------------------------------------------------
// Prep: f32 -> bf16 copies, fp32 row norms (from ORIGINAL f32 values),
// init dpos accumulators to 0 and dneg accumulator to +inf.
// One wave per row; lane handles 2 contiguous elements (float2, coalesced).
// ---------------------------------------------------------------------------
__global__ __launch_bounds__(256) void prep_kernel(
    const float* __restrict__ anchor, const float* __restrict__ positive,
    const float* __restrict__ negative,
    short* __restrict__ bfA, short* __restrict__ bfP, short* __restrict__ bfN,
    float* __restrict__ nA, float* __restrict__ nP, float* __restrict__ nN,
    unsigned* __restrict__ dposBits, unsigned* __restrict__ dnegBits)
{
    const int row  = blockIdx.x * 4 + (threadIdx.x >> 6);
    const int lane = threadIdx.x & 63;

    const float* src; short* dst; float* nrm; int r;
    if (row < B_ANCH) {
        src = anchor; dst = bfA; nrm = nA; r = row;
        if (lane == 0) dposBits[row] = 0u;           // max identity (sq clamped >= 0)
    } else if (row < B_ANCH + P_POS) {
        src = positive; dst = bfP; nrm = nP; r = row - B_ANCH;
    } else {
        src = negative; dst = bfN; nrm = nN; r = row - (B_ANCH + P_POS);
    }
    if (blockIdx.x == 0 && threadIdx.x == 0) *dnegBits = 0x7F800000u;  // +inf

    float2 v = *(const float2*)(src + (size_t)r * DDIM + lane * 2);
    short2 o; o.x = f2bf(v.x); o.y = f2bf(v.y);
    *(short2*)(dst + (size_t)r * DDIM + lane * 2) = o;

    float ss = v.x * v.x + v.y * v.y;
    #pragma unroll
    for (int m = 1; m < 64; m <<= 1) ss += __shfl_xor(ss, m);
    if (lane == 0) nrm[r] = ss;
}

// ---------------------------------------------------------------------------
// Tiled distance + reduce. 64x64 output tile per block (4 waves x 16 rows).
// MODE 0: per-row max (positives)  -> atomicMax(dposBits[row])
// MODE 1: global min  (negatives)  -> one atomicMin(dnegBits) per block
// mfma_f32_16x16x32_bf16:
//   A frag: lane l holds A[r0 + (l&15)][8*(l>>4) + j], j=0..7
//   B frag: lane l holds Y[c0 + (l&15)][8*(l>>4) + j]   (Y row as B column)
//   D:      lane l, reg r -> row r0 + 4*(l>>4) + r, col c0 + (l&15)
// ---------------------------------------------------------------------------
template<int MODE>
__global__ __launch_bounds__(256) void dist_reduce_kernel(
    const short* __restrict__ A, const short* __restrict__ Y,
    const float* __restrict__ nA, const float* __restrict__ nY,
    unsigned* __restrict__ dposBits, unsigned* __restrict__ dnegBits)
{
    const int wid  = threadIdx.x >> 6;
    const int lane = threadIdx.x & 63;
    const int lm = lane & 15, lk = lane >> 4;
    const int r0 = blockIdx.y * 64 + wid * 16;
    const int c0 = blockIdx.x * 64;

    // A fragments for the 4 K-steps (K=128 = 4 * 32), reused across col tiles.
    bf16x8 a[4];
    const short* ap = A + (size_t)(r0 + lm) * DDIM + lk * 8;
    #pragma unroll
    for (int s = 0; s < 4; ++s) a[s] = *(const bf16x8*)(ap + s * 32);

    f32x4 acc[4];
    #pragma unroll
    for (int ct = 0; ct < 4; ++ct) {
        const short* yp = Y + (size_t)(c0 + ct * 16 + lm) * DDIM + lk * 8;
        f32x4 c = {0.f, 0.f, 0.f, 0.f};
        #pragma unroll
        for (int s = 0; s < 4; ++s) {
            bf16x8 b = *(const bf16x8*)(yp + s * 32);
            c = __builtin_amdgcn_mfma_f32_16x16x32_bf16(a[s], b, c, 0, 0, 0);
        }
        acc[ct] = c;
    }

    float na[4];
    #pragma unroll
    for (int r = 0; r < 4; ++r) na[r] = nA[r0 + 4 * lk + r];

    if (MODE == 0) {
        float rowmax[4] = {0.f, 0.f, 0.f, 0.f};
        #pragma unroll
        for (int ct = 0; ct < 4; ++ct) {
            float ny = nY[c0 + ct * 16 + lm];
            #pragma unroll
            for (int r = 0; r < 4; ++r) {
                float sq = na[r] + ny - 2.f * acc[ct][r];
                rowmax[r] = fmaxf(rowmax[r], sq);
            }
        }
        // reduce across the 16 lanes that share the same 4 rows
        #pragma unroll
        for (int m = 1; m < 16; m <<= 1) {
            #pragma unroll
            for (int r = 0; r < 4; ++r)
                rowmax[r] = fmaxf(rowmax[r], __shfl_xor(rowmax[r], m));
        }
        if (lm == 0) {
            #pragma unroll
            for (int r = 0; r < 4; ++r)
                atomicMax(dposBits + (r0 + 4 * lk + r), __float_as_uint(rowmax[r]));
        }
    } else {
        float mn = 3.4e38f;
        #pragma unroll
        for (int ct = 0; ct < 4; ++ct) {
            float ny = nY[c0 + ct * 16 + lm];
            #pragma unroll
            for (int r = 0; r < 4; ++r) {
                float sq = na[r] + ny - 2.f * acc[ct][r];
                mn = fminf(mn, fmaxf(sq, 0.f));
            }
        }
        #pragma unroll
        for (int m = 1; m < 64; m <<= 1) mn = fminf(mn, __shfl_xor(mn, m));
        __shared__ float wmin[4];
        if (lane == 0) wmin[wid] = mn;
        __syncthreads();
        if (threadIdx.x == 0) {
            float m2 = fminf(fminf(wmin[0], wmin[1]), fminf(wmin[2], wmin[3]));
            atomicMin(dnegBits, __float_as_uint(m2));
        }
    }
}

// ---------------------------------------------------------------------------
// Finalize: mean(relu(sqrt(dpos_sq) - sqrt(dneg_sq) + margin))
// ---------------------------------------------------------------------------
__global__ __launch_bounds__(256) void finalize_kernel(
    const unsigned* __restrict__ dposBits, const unsigned* __restrict__ dnegBits,
    float* __restrict__ out)
{
    const float dneg = sqrtf(__uint_as_float(*dnegBits));
    float s = 0.f;
    for (int i = threadIdx.x; i < B_ANCH; i += 256) {
        float dp = sqrtf(__uint_as_float(dposBits[i]));
        s += fmaxf(dp - dneg + MARGIN_F, 0.f);
    }
    #pragma unroll
    for (int m = 1; m < 64; m <<= 1) s += __shfl_xor(s, m);
    __shared__ float ws[4];
    const int wid = threadIdx.x >> 6, lane = threadIdx.x & 63;
    if (lane == 0) ws[wid] = s;
    __syncthreads();
    if (threadIdx.x == 0)
        out[0] = (ws[0] + ws[1] + ws[2] + ws[3]) * (1.f / (float)B_ANCH);
}

// ---------------------------------------------------------------------------
extern "C" void kernel_launch(void* const* d_in, const int* in_sizes, int n_in,
                              void* d_out, int out_size, void* d_ws, size_t ws_size,
                              hipStream_t stream) {
    const float* anchor   = (const float*)d_in[0];
    const float* positive = (const float*)d_in[1];
    const float* negative = (const float*)d_in[2];
    float* out = (float*)d_out;

    char* ws = (char*)d_ws;
    size_t off = 0;
    auto alloc = [&](size_t bytes) { char* p = ws + off; off = (off + bytes + 255) & ~(size_t)255; return p; };

    short* bfA = (short*)alloc((size_t)B_ANCH * DDIM * 2);
    short* bfP = (short*)alloc((size_t)P_POS  * DDIM * 2);
    short* bfN = (short*)alloc((size_t)N_NEG  * DDIM * 2);
    float* nA  = (float*)alloc((size_t)B_ANCH * 4);
    float* nP  = (float*)alloc((size_t)P_POS  * 4);
    float* nN  = (float*)alloc((size_t)N_NEG  * 4);
    unsigned* dposBits = (unsigned*)alloc((size_t)B_ANCH * 4);
    unsigned* dnegBits = (unsigned*)alloc(4);

    // 1. prep: one wave per row, 4 rows per block
    const int totalRows = B_ANCH + P_POS + N_NEG;
    prep_kernel<<<totalRows / 4, 256, 0, stream>>>(
        anchor, positive, negative, bfA, bfP, bfN, nA, nP, nN, dposBits, dnegBits);

    // 2. positives: per-anchor max distance
    dist_reduce_kernel<0><<<dim3(P_POS / 64, B_ANCH / 64), 256, 0, stream>>>(
        bfA, bfP, nA, nP, dposBits, dnegBits);

    // 3. negatives: global min distance
    dist_reduce_kernel<1><<<dim3(N_NEG / 64, B_ANCH / 64), 256, 0, stream>>>(
        bfA, bfN, nA, nN, dposBits, dnegBits);

    // 4. finalize
    finalize_kernel<<<1, 256, 0, stream>>>(dposBits, dnegBits, out);
}

// Round 2
// 106.195 us; speedup vs baseline: 2.2708x; 2.2708x over previous
//
#include <hip/hip_runtime.h>
#include <hip/hip_bf16.h>

#define MARGIN_F 0.25f

// Problem constants (fixed by setup_inputs).
#define B_ANCH 2048
#define P_POS  2048
#define N_NEG  32768   // 2048 * 16
#define DDIM   128

typedef __attribute__((ext_vector_type(8))) short bf16x8;   // 8 bf16 = 4 VGPRs
typedef __attribute__((ext_vector_type(4))) float f32x4;

__device__ __forceinline__ short f2bf(float x) {
    __hip_bfloat16 h = __float2bfloat16(x);
    return *reinterpret_cast<short*>(&h);
}

// ---------------------------------------------------------------------------
// Prep: f32 -> bf16 copies, fp32 row norms (from ORIGINAL f32 values),
// init dpos accumulators to 0 and dneg accumulator to +inf.
// One wave per row; lane handles 2 contiguous elements (float2, coalesced).
// ---------------------------------------------------------------------------
__global__ __launch_bounds__(256) void prep_kernel(
    const float* __restrict__ anchor, const float* __restrict__ positive,
    const float* __restrict__ negative,
    short* __restrict__ bfA, short* __restrict__ bfP, short* __restrict__ bfN,
    float* __restrict__ nA, float* __restrict__ nP, float* __restrict__ nN,
    unsigned* __restrict__ dposBits, unsigned* __restrict__ dnegBits)
{
    const int row  = blockIdx.x * 4 + (threadIdx.x >> 6);
    const int lane = threadIdx.x & 63;

    const float* src; short* dst; float* nrm; int r;
    if (row < B_ANCH) {
        src = anchor; dst = bfA; nrm = nA; r = row;
        if (lane == 0) dposBits[row] = 0u;           // max identity (sq clamped >= 0)
    } else if (row < B_ANCH + P_POS) {
        src = positive; dst = bfP; nrm = nP; r = row - B_ANCH;
    } else {
        src = negative; dst = bfN; nrm = nN; r = row - (B_ANCH + P_POS);
    }
    if (blockIdx.x == 0 && threadIdx.x == 0) *dnegBits = 0x7F800000u;  // +inf

    float2 v = *(const float2*)(src + (size_t)r * DDIM + lane * 2);
    short2 o; o.x = f2bf(v.x); o.y = f2bf(v.y);
    *(short2*)(dst + (size_t)r * DDIM + lane * 2) = o;

    float ss = v.x * v.x + v.y * v.y;
    #pragma unroll
    for (int m = 1; m < 64; m <<= 1) ss += __shfl_xor(ss, m);
    if (lane == 0) nrm[r] = ss;
}

// ---------------------------------------------------------------------------
// Tiled distance + reduce. 128x128 block tile, 4 waves (2x2), each wave
// computes a 64x64 sub-tile with 4x4 f32x4 accumulators (64 MFMAs/wave).
// All fragments loaded directly from global (inputs are L2/L3-resident).
// MODE 0: per-row max (positives)  -> atomicMax(dposBits[row])
// MODE 1: global min  (negatives)  -> one atomicMin(dnegBits) per block
// mfma_f32_16x16x32_bf16 layouts (verified by R0 absmax=0):
//   A frag: lane l holds A[r0 + (l&15)][s*32 + 8*(l>>4) + j], j=0..7
//   B frag: lane l holds Y[c0 + (l&15)][s*32 + 8*(l>>4) + j]
//   D:      lane l, reg r -> row r0 + 4*(l>>4) + r, col c0 + (l&15)
// ---------------------------------------------------------------------------
template<int MODE>
__global__ __launch_bounds__(256, 2) void dist_reduce_kernel(
    const short* __restrict__ A, const short* __restrict__ Y,
    const float* __restrict__ nA, const float* __restrict__ nY,
    unsigned* __restrict__ dposBits, unsigned* __restrict__ dnegBits)
{
    const int wid  = threadIdx.x >> 6;
    const int lane = threadIdx.x & 63;
    const int lm = lane & 15, lk = lane >> 4;
    const int wr = wid >> 1, wc = wid & 1;
    const int r0 = blockIdx.y * 128 + wr * 64;   // wave's first anchor row
    const int c0 = blockIdx.x * 128 + wc * 64;   // wave's first Y row (output col)

    // A fragments: 64 rows x 128 cols per wave, held in registers (64 VGPRs).
    bf16x8 a[4][4];
    #pragma unroll
    for (int m = 0; m < 4; ++m) {
        const short* ap = A + (size_t)(r0 + m * 16 + lm) * DDIM + lk * 8;
        #pragma unroll
        for (int s = 0; s < 4; ++s) a[m][s] = *(const bf16x8*)(ap + s * 32);
    }

    f32x4 acc[4][4];
    #pragma unroll
    for (int m = 0; m < 4; ++m)
        #pragma unroll
        for (int n = 0; n < 4; ++n) acc[m][n] = f32x4{0.f, 0.f, 0.f, 0.f};

    #pragma unroll
    for (int n = 0; n < 4; ++n) {
        const short* yp = Y + (size_t)(c0 + n * 16 + lm) * DDIM + lk * 8;
        bf16x8 b[4];
        #pragma unroll
        for (int s = 0; s < 4; ++s) b[s] = *(const bf16x8*)(yp + s * 32);
        #pragma unroll
        for (int s = 0; s < 4; ++s)
            #pragma unroll
            for (int m = 0; m < 4; ++m)
                acc[m][n] = __builtin_amdgcn_mfma_f32_16x16x32_bf16(a[m][s], b[s], acc[m][n], 0, 0, 0);
    }

    // Row norms for this lane's output rows: row = r0 + m*16 + 4*lk + r
    float na[4][4];
    #pragma unroll
    for (int m = 0; m < 4; ++m)
        #pragma unroll
        for (int r = 0; r < 4; ++r)
            na[m][r] = nA[r0 + m * 16 + 4 * lk + r];

    if (MODE == 0) {
        float rowmax[4][4];
        #pragma unroll
        for (int m = 0; m < 4; ++m)
            #pragma unroll
            for (int r = 0; r < 4; ++r) rowmax[m][r] = 0.f;
        #pragma unroll
        for (int n = 0; n < 4; ++n) {
            float ny = nY[c0 + n * 16 + lm];
            #pragma unroll
            for (int m = 0; m < 4; ++m)
                #pragma unroll
                for (int r = 0; r < 4; ++r) {
                    float sq = na[m][r] + ny - 2.f * acc[m][n][r];
                    rowmax[m][r] = fmaxf(rowmax[m][r], sq);
                }
        }
        // reduce across the 16 lanes sharing the same rows (lk fixed)
        #pragma unroll
        for (int msk = 1; msk < 16; msk <<= 1)
            #pragma unroll
            for (int m = 0; m < 4; ++m)
                #pragma unroll
                for (int r = 0; r < 4; ++r)
                    rowmax[m][r] = fmaxf(rowmax[m][r], __shfl_xor(rowmax[m][r], msk));
        if (lm == 0) {
            #pragma unroll
            for (int m = 0; m < 4; ++m)
                #pragma unroll
                for (int r = 0; r < 4; ++r)
                    atomicMax(dposBits + (r0 + m * 16 + 4 * lk + r),
                              __float_as_uint(rowmax[m][r]));
        }
    } else {
        float mn = 3.4e38f;
        #pragma unroll
        for (int n = 0; n < 4; ++n) {
            float ny = nY[c0 + n * 16 + lm];
            #pragma unroll
            for (int m = 0; m < 4; ++m)
                #pragma unroll
                for (int r = 0; r < 4; ++r) {
                    float sq = na[m][r] + ny - 2.f * acc[m][n][r];
                    mn = fminf(mn, fmaxf(sq, 0.f));
                }
        }
        #pragma unroll
        for (int msk = 1; msk < 64; msk <<= 1) mn = fminf(mn, __shfl_xor(mn, msk));
        __shared__ float wmin[4];
        if (lane == 0) wmin[wid] = mn;
        __syncthreads();
        if (threadIdx.x == 0) {
            float m2 = fminf(fminf(wmin[0], wmin[1]), fminf(wmin[2], wmin[3]));
            atomicMin(dnegBits, __float_as_uint(m2));
        }
    }
}

// ---------------------------------------------------------------------------
// Finalize: mean(relu(sqrt(dpos_sq) - sqrt(dneg_sq) + margin))
// ---------------------------------------------------------------------------
__global__ __launch_bounds__(256) void finalize_kernel(
    const unsigned* __restrict__ dposBits, const unsigned* __restrict__ dnegBits,
    float* __restrict__ out)
{
    const float dneg = sqrtf(__uint_as_float(*dnegBits));
    float s = 0.f;
    for (int i = threadIdx.x; i < B_ANCH; i += 256) {
        float dp = sqrtf(__uint_as_float(dposBits[i]));
        s += fmaxf(dp - dneg + MARGIN_F, 0.f);
    }
    #pragma unroll
    for (int m = 1; m < 64; m <<= 1) s += __shfl_xor(s, m);
    __shared__ float ws[4];
    const int wid = threadIdx.x >> 6, lane = threadIdx.x & 63;
    if (lane == 0) ws[wid] = s;
    __syncthreads();
    if (threadIdx.x == 0)
        out[0] = (ws[0] + ws[1] + ws[2] + ws[3]) * (1.f / (float)B_ANCH);
}

// ---------------------------------------------------------------------------
extern "C" void kernel_launch(void* const* d_in, const int* in_sizes, int n_in,
                              void* d_out, int out_size, void* d_ws, size_t ws_size,
                              hipStream_t stream) {
    const float* anchor   = (const float*)d_in[0];
    const float* positive = (const float*)d_in[1];
    const float* negative = (const float*)d_in[2];
    float* out = (float*)d_out;

    char* ws = (char*)d_ws;
    size_t off = 0;
    auto alloc = [&](size_t bytes) { char* p = ws + off; off = (off + bytes + 255) & ~(size_t)255; return p; };

    short* bfA = (short*)alloc((size_t)B_ANCH * DDIM * 2);
    short* bfP = (short*)alloc((size_t)P_POS  * DDIM * 2);
    short* bfN = (short*)alloc((size_t)N_NEG  * DDIM * 2);
    float* nA  = (float*)alloc((size_t)B_ANCH * 4);
    float* nP  = (float*)alloc((size_t)P_POS  * 4);
    float* nN  = (float*)alloc((size_t)N_NEG  * 4);
    unsigned* dposBits = (unsigned*)alloc((size_t)B_ANCH * 4);
    unsigned* dnegBits = (unsigned*)alloc(4);

    // 1. prep: one wave per row, 4 rows per block
    const int totalRows = B_ANCH + P_POS + N_NEG;
    prep_kernel<<<totalRows / 4, 256, 0, stream>>>(
        anchor, positive, negative, bfA, bfP, bfN, nA, nP, nN, dposBits, dnegBits);

    // 2. positives: per-anchor max distance (128x128 tiles)
    dist_reduce_kernel<0><<<dim3(P_POS / 128, B_ANCH / 128), 256, 0, stream>>>(
        bfA, bfP, nA, nP, dposBits, dnegBits);

    // 3. negatives: global min distance (128x128 tiles)
    dist_reduce_kernel<1><<<dim3(N_NEG / 128, B_ANCH / 128), 256, 0, stream>>>(
        bfA, bfN, nA, nN, dposBits, dnegBits);

    // 4. finalize
    finalize_kernel<<<1, 256, 0, stream>>>(dposBits, dnegBits, out);
}

// Round 3
// 50.112 us; speedup vs baseline: 4.8121x; 2.1192x over previous
//
#include <hip/hip_runtime.h>
#include <hip/hip_bf16.h>

#define MARGIN_F 0.25f

// Problem constants (fixed by setup_inputs).
#define B_ANCH 2048
#define P_POS  2048
#define N_NEG  32768   // 2048 * 16
#define DDIM   128

typedef __attribute__((ext_vector_type(8))) short bf16x8;   // 8 bf16 = 4 VGPRs
typedef __attribute__((ext_vector_type(4))) float f32x4;

__device__ __forceinline__ short f2bf(float x) {
    __hip_bfloat16 h = __float2bfloat16(x);
    return *reinterpret_cast<short*>(&h);
}

// ---------------------------------------------------------------------------
// Prep: f32 -> bf16 in FRAGMENT-MAJOR layout + fp32 row norms + accumulator
// init. Packed layout: for 16-row tile T, k-step s (32 dims), lane l
// (lm=l&15 row-in-tile, lk=l>>4 dim-group):
//   packed[((T*4+s)*64 + l)*8 + j] = bf16( src[(T*16+lm)*128 + s*32+lk*8+j] )
// One wave per 16-row tile; each lane produces 4 x 16B chunks (coalesced 1KB
// wave writes). Row norms in fp32 from ORIGINAL f32 (lane covers 32 dims of
// its row; reduce across the 4 lanes sharing lm via xor 16/32).
// ---------------------------------------------------------------------------
__global__ __launch_bounds__(256) void prep_kernel(
    const float* __restrict__ anchor, const float* __restrict__ positive,
    const float* __restrict__ negative,
    short* __restrict__ pA, short* __restrict__ pP, short* __restrict__ pN,
    float* __restrict__ nA, float* __restrict__ nP, float* __restrict__ nN,
    unsigned* __restrict__ dposBits, unsigned* __restrict__ dnegBits)
{
    const int tile = blockIdx.x * 4 + (threadIdx.x >> 6);   // global 16-row tile
    const int lane = threadIdx.x & 63;
    const int lm = lane & 15, lk = lane >> 4;

    const float* src; short* dst; float* nrm; int t;
    const int TA = B_ANCH / 16, TP = P_POS / 16;
    if (tile < TA) {
        src = anchor; dst = pA; nrm = nA; t = tile;
        if (lm == lane) dposBits[tile * 16 + lm] = 0u;      // lanes 0..15
    } else if (tile < TA + TP) {
        src = positive; dst = pP; nrm = nP; t = tile - TA;
    } else {
        src = negative; dst = pN; nrm = nN; t = tile - TA - TP;
    }
    if (blockIdx.x == 0 && threadIdx.x == 0) *dnegBits = 0x7F800000u;  // +inf

    const int row = t * 16 + lm;
    float ss = 0.f;
    #pragma unroll
    for (int s = 0; s < 4; ++s) {
        const float* sp = src + (size_t)row * DDIM + s * 32 + lk * 8;
        float4 v0 = *(const float4*)sp;
        float4 v1 = *(const float4*)(sp + 4);
        ss += v0.x*v0.x + v0.y*v0.y + v0.z*v0.z + v0.w*v0.w
            + v1.x*v1.x + v1.y*v1.y + v1.z*v1.z + v1.w*v1.w;
        bf16x8 o;
        o[0]=f2bf(v0.x); o[1]=f2bf(v0.y); o[2]=f2bf(v0.z); o[3]=f2bf(v0.w);
        o[4]=f2bf(v1.x); o[5]=f2bf(v1.y); o[6]=f2bf(v1.z); o[7]=f2bf(v1.w);
        *(bf16x8*)(dst + ((size_t)(t * 4 + s) * 64 + lane) * 8) = o;
    }
    // reduce over the 4 lanes (lk=0..3) sharing this row
    ss += __shfl_xor(ss, 16);
    ss += __shfl_xor(ss, 32);
    if (lk == 0) nrm[row] = ss;
}

// ---------------------------------------------------------------------------
// Tiled distance + reduce on fragment-major data. 128x128 block tile,
// 4 waves (2x2), each wave 64x64 via 4x4 f32x4 accumulators. Each block
// loops over CT column tiles (A frags stay in registers, reused CT times).
// Every fragment load is one coalesced 1KB wave transaction (lane i -> +16B).
// MODE 0: per-row max (positives)  -> atomicMax(dposBits[row])
// MODE 1: global min  (negatives)  -> one atomicMin(dnegBits) per block
// ---------------------------------------------------------------------------
template<int MODE, int CT>
__global__ __launch_bounds__(256, 2) void dist_reduce_kernel(
    const short* __restrict__ pA, const short* __restrict__ pY,
    const float* __restrict__ nA, const float* __restrict__ nY,
    unsigned* __restrict__ dposBits, unsigned* __restrict__ dnegBits)
{
    const int wid  = threadIdx.x >> 6;
    const int lane = threadIdx.x & 63;
    const int lm = lane & 15, lk = lane >> 4;
    const int wr = wid >> 1, wc = wid & 1;
    const int rt0 = blockIdx.y * 8 + wr * 4;   // first 16-row A tile of this wave

    const bf16x8* Af = (const bf16x8*)pA;
    const bf16x8* Yf = (const bf16x8*)pY;

    // A fragments: 64 rows x 128 dims, held in registers across all col tiles.
    bf16x8 a[4][4];
    #pragma unroll
    for (int m = 0; m < 4; ++m)
        #pragma unroll
        for (int s = 0; s < 4; ++s)
            a[m][s] = Af[(size_t)((rt0 + m) * 4 + s) * 64 + lane];

    float na[4][4];
    #pragma unroll
    for (int m = 0; m < 4; ++m)
        #pragma unroll
        for (int r = 0; r < 4; ++r)
            na[m][r] = nA[(rt0 + m) * 16 + 4 * lk + r];

    float rowmax[4][4];
    float mn = 3.4e38f;
    if (MODE == 0) {
        #pragma unroll
        for (int m = 0; m < 4; ++m)
            #pragma unroll
            for (int r = 0; r < 4; ++r) rowmax[m][r] = 0.f;
    }

    #pragma unroll 1
    for (int ct = 0; ct < CT; ++ct) {
        const int nt0 = (blockIdx.x * CT + ct) * 8 + wc * 4;  // first 16-col tile

        f32x4 acc[4][4];
        #pragma unroll
        for (int m = 0; m < 4; ++m)
            #pragma unroll
            for (int n = 0; n < 4; ++n) acc[m][n] = f32x4{0.f, 0.f, 0.f, 0.f};

        #pragma unroll
        for (int n = 0; n < 4; ++n) {
            bf16x8 b[4];
            #pragma unroll
            for (int s = 0; s < 4; ++s)
                b[s] = Yf[(size_t)((nt0 + n) * 4 + s) * 64 + lane];
            #pragma unroll
            for (int s = 0; s < 4; ++s)
                #pragma unroll
                for (int m = 0; m < 4; ++m)
                    acc[m][n] = __builtin_amdgcn_mfma_f32_16x16x32_bf16(a[m][s], b[s], acc[m][n], 0, 0, 0);
        }

        #pragma unroll
        for (int n = 0; n < 4; ++n) {
            float ny = nY[(nt0 + n) * 16 + lm];
            #pragma unroll
            for (int m = 0; m < 4; ++m)
                #pragma unroll
                for (int r = 0; r < 4; ++r) {
                    float sq = na[m][r] + ny - 2.f * acc[m][n][r];
                    if (MODE == 0) rowmax[m][r] = fmaxf(rowmax[m][r], sq);
                    else           mn = fminf(mn, fmaxf(sq, 0.f));
                }
        }
    }

    if (MODE == 0) {
        // reduce across the 16 lanes sharing the same rows (lk fixed)
        #pragma unroll
        for (int msk = 1; msk < 16; msk <<= 1)
            #pragma unroll
            for (int m = 0; m < 4; ++m)
                #pragma unroll
                for (int r = 0; r < 4; ++r)
                    rowmax[m][r] = fmaxf(rowmax[m][r], __shfl_xor(rowmax[m][r], msk));
        if (lm == 0) {
            #pragma unroll
            for (int m = 0; m < 4; ++m)
                #pragma unroll
                for (int r = 0; r < 4; ++r)
                    atomicMax(dposBits + ((rt0 + m) * 16 + 4 * lk + r),
                              __float_as_uint(rowmax[m][r]));
        }
    } else {
        #pragma unroll
        for (int msk = 1; msk < 64; msk <<= 1) mn = fminf(mn, __shfl_xor(mn, msk));
        __shared__ float wmin[4];
        if (lane == 0) wmin[wid] = mn;
        __syncthreads();
        if (threadIdx.x == 0) {
            float m2 = fminf(fminf(wmin[0], wmin[1]), fminf(wmin[2], wmin[3]));
            atomicMin(dnegBits, __float_as_uint(m2));
        }
    }
}

// ---------------------------------------------------------------------------
// Finalize: mean(relu(sqrt(dpos_sq) - sqrt(dneg_sq) + margin))
// ---------------------------------------------------------------------------
__global__ __launch_bounds__(256) void finalize_kernel(
    const unsigned* __restrict__ dposBits, const unsigned* __restrict__ dnegBits,
    float* __restrict__ out)
{
    const float dneg = sqrtf(__uint_as_float(*dnegBits));
    float s = 0.f;
    for (int i = threadIdx.x; i < B_ANCH; i += 256) {
        float dp = sqrtf(__uint_as_float(dposBits[i]));
        s += fmaxf(dp - dneg + MARGIN_F, 0.f);
    }
    #pragma unroll
    for (int m = 1; m < 64; m <<= 1) s += __shfl_xor(s, m);
    __shared__ float ws[4];
    const int wid = threadIdx.x >> 6, lane = threadIdx.x & 63;
    if (lane == 0) ws[wid] = s;
    __syncthreads();
    if (threadIdx.x == 0)
        out[0] = (ws[0] + ws[1] + ws[2] + ws[3]) * (1.f / (float)B_ANCH);
}

// ---------------------------------------------------------------------------
extern "C" void kernel_launch(void* const* d_in, const int* in_sizes, int n_in,
                              void* d_out, int out_size, void* d_ws, size_t ws_size,
                              hipStream_t stream) {
    const float* anchor   = (const float*)d_in[0];
    const float* positive = (const float*)d_in[1];
    const float* negative = (const float*)d_in[2];
    float* out = (float*)d_out;

    char* ws = (char*)d_ws;
    size_t off = 0;
    auto alloc = [&](size_t bytes) { char* p = ws + off; off = (off + bytes + 255) & ~(size_t)255; return p; };

    short* pA = (short*)alloc((size_t)B_ANCH * DDIM * 2);
    short* pP = (short*)alloc((size_t)P_POS  * DDIM * 2);
    short* pN = (short*)alloc((size_t)N_NEG  * DDIM * 2);
    float* nA  = (float*)alloc((size_t)B_ANCH * 4);
    float* nP  = (float*)alloc((size_t)P_POS  * 4);
    float* nN  = (float*)alloc((size_t)N_NEG  * 4);
    unsigned* dposBits = (unsigned*)alloc((size_t)B_ANCH * 4);
    unsigned* dnegBits = (unsigned*)alloc(4);

    // 1. prep: one wave per 16-row tile, 4 tiles per block
    const int totalTiles = (B_ANCH + P_POS + N_NEG) / 16;   // 2304
    prep_kernel<<<totalTiles / 4, 256, 0, stream>>>(
        anchor, positive, negative, pA, pP, pN, nA, nP, nN, dposBits, dnegBits);

    // 2. positives: per-anchor max distance. 128x128 tile, 1 col tile/block.
    dist_reduce_kernel<0, 1><<<dim3(P_POS / 128, B_ANCH / 128), 256, 0, stream>>>(
        pA, pP, nA, nP, dposBits, dnegBits);

    // 3. negatives: global min distance. 128x128 tile, 8 col tiles/block.
    dist_reduce_kernel<1, 8><<<dim3(N_NEG / (128 * 8), B_ANCH / 128), 256, 0, stream>>>(
        pA, pN, nA, nN, dposBits, dnegBits);

    // 4. finalize
    finalize_kernel<<<1, 256, 0, stream>>>(dposBits, dnegBits, out);
}

// Round 4
// 36.353 us; speedup vs baseline: 6.6334x; 1.3785x over previous
//
#include <hip/hip_runtime.h>
#include <hip/hip_bf16.h>

#define MARGIN_F 0.25f

// Problem constants (fixed by setup_inputs).
#define B_ANCH 2048
#define P_POS  2048
#define N_NEG  32768   // 2048 * 16
#define DDIM   128

typedef __attribute__((ext_vector_type(8))) short bf16x8;   // 8 bf16 = 4 VGPRs
typedef __attribute__((ext_vector_type(4))) float f32x4;

__device__ __forceinline__ short f2bf(float x) {
    __hip_bfloat16 h = __float2bfloat16(x);
    return *reinterpret_cast<short*>(&h);
}

// ---------------------------------------------------------------------------
// Prep: f32 -> bf16 in FRAGMENT-MAJOR layout + fp32 row norms + accumulator
// init. Packed layout: for 16-row tile T, k-step s (32 dims), lane l
// (lm=l&15 row-in-tile, lk=l>>4 dim-group):
//   packed[((T*4+s)*64 + l)*8 + j] = bf16( src[(T*16+lm)*128 + s*32+lk*8+j] )
// ---------------------------------------------------------------------------
__global__ __launch_bounds__(256) void prep_kernel(
    const float* __restrict__ anchor, const float* __restrict__ positive,
    const float* __restrict__ negative,
    short* __restrict__ pA, short* __restrict__ pP, short* __restrict__ pN,
    float* __restrict__ nA, float* __restrict__ nP, float* __restrict__ nN,
    unsigned* __restrict__ dposBits, unsigned* __restrict__ dnegBits)
{
    const int tile = blockIdx.x * 4 + (threadIdx.x >> 6);   // global 16-row tile
    const int lane = threadIdx.x & 63;
    const int lm = lane & 15, lk = lane >> 4;

    const float* src; short* dst; float* nrm; int t;
    const int TA = B_ANCH / 16, TP = P_POS / 16;
    if (tile < TA) {
        src = anchor; dst = pA; nrm = nA; t = tile;
        if (lm == lane) dposBits[tile * 16 + lm] = 0u;      // lanes 0..15
    } else if (tile < TA + TP) {
        src = positive; dst = pP; nrm = nP; t = tile - TA;
    } else {
        src = negative; dst = pN; nrm = nN; t = tile - TA - TP;
    }
    if (blockIdx.x == 0 && threadIdx.x == 0) *dnegBits = 0x7F800000u;  // +inf

    const int row = t * 16 + lm;
    float ss = 0.f;
    #pragma unroll
    for (int s = 0; s < 4; ++s) {
        const float* sp = src + (size_t)row * DDIM + s * 32 + lk * 8;
        float4 v0 = *(const float4*)sp;
        float4 v1 = *(const float4*)(sp + 4);
        ss += v0.x*v0.x + v0.y*v0.y + v0.z*v0.z + v0.w*v0.w
            + v1.x*v1.x + v1.y*v1.y + v1.z*v1.z + v1.w*v1.w;
        bf16x8 o;
        o[0]=f2bf(v0.x); o[1]=f2bf(v0.y); o[2]=f2bf(v0.z); o[3]=f2bf(v0.w);
        o[4]=f2bf(v1.x); o[5]=f2bf(v1.y); o[6]=f2bf(v1.z); o[7]=f2bf(v1.w);
        *(bf16x8*)(dst + ((size_t)(t * 4 + s) * 64 + lane) * 8) = o;
    }
    ss += __shfl_xor(ss, 16);
    ss += __shfl_xor(ss, 32);
    if (lk == 0) nrm[row] = ss;
}

// ---------------------------------------------------------------------------
// Distance + reduce tile body. 128-row block tile, 4 waves (2x2); each wave
// owns 64 rows x 64 cols per column-tile group and loops over G = CT*4
// 16-col groups with a depth-2 rolling B prefetch (b[3][4], static indexing).
// Tracks red[m][r] = min/max over cols of (|y|^2 - 2 a.y); |a|^2 added once
// at the end (clamp at 0 commutes with min/max).
// MODE 0: per-row max -> atomicMax(dposBits[row]); MODE 1: global min ->
// one atomicMin(dnegBits) per block.
// ---------------------------------------------------------------------------
template<int MODE, int CT>
__device__ __forceinline__ void dist_tile(
    const bf16x8* __restrict__ Af, const bf16x8* __restrict__ Yf,
    const float* __restrict__ nA, const float* __restrict__ nY,
    int by, int bx,
    unsigned* __restrict__ dposBits, unsigned* __restrict__ dnegBits)
{
    const int wid  = threadIdx.x >> 6;
    const int lane = threadIdx.x & 63;
    const int lm = lane & 15, lk = lane >> 4;
    const int wr = wid >> 1, wc = wid & 1;
    const int rt0 = by * 8 + wr * 4;          // first 16-row A tile of this wave

    // A fragments: 64 rows x 128 dims, resident across all column groups.
    bf16x8 a[4][4];
    #pragma unroll
    for (int m = 0; m < 4; ++m)
        #pragma unroll
        for (int s = 0; s < 4; ++s)
            a[m][s] = Af[(size_t)((rt0 + m) * 4 + s) * 64 + lane];

    float red[4][4];
    #pragma unroll
    for (int m = 0; m < 4; ++m)
        #pragma unroll
        for (int r = 0; r < 4; ++r)
            red[m][r] = (MODE == 0) ? -3.4e38f : 3.4e38f;

    constexpr int G = CT * 4;

    bf16x8 b[3][4];
    float nyv[3];
    #pragma unroll
    for (int p = 0; p < 2 && p < G; ++p) {
        const int ctile = (bx * CT + (p >> 2)) * 8 + wc * 4 + (p & 3);
        #pragma unroll
        for (int s = 0; s < 4; ++s)
            b[p][s] = Yf[(size_t)(ctile * 4 + s) * 64 + lane];
        nyv[p] = nY[ctile * 16 + lm];
    }

    #pragma unroll
    for (int g = 0; g < G; ++g) {
        const int gp = g + 2;
        if (gp < G) {
            const int ctile = (bx * CT + (gp >> 2)) * 8 + wc * 4 + (gp & 3);
            #pragma unroll
            for (int s = 0; s < 4; ++s)
                b[gp % 3][s] = Yf[(size_t)(ctile * 4 + s) * 64 + lane];
            nyv[gp % 3] = nY[ctile * 16 + lm];
        }
        f32x4 acc[4];
        #pragma unroll
        for (int m = 0; m < 4; ++m) acc[m] = f32x4{0.f, 0.f, 0.f, 0.f};
        #pragma unroll
        for (int s = 0; s < 4; ++s)
            #pragma unroll
            for (int m = 0; m < 4; ++m)
                acc[m] = __builtin_amdgcn_mfma_f32_16x16x32_bf16(a[m][s], b[g % 3][s], acc[m], 0, 0, 0);
        const float ny = nyv[g % 3];
        #pragma unroll
        for (int m = 0; m < 4; ++m)
            #pragma unroll
            for (int r = 0; r < 4; ++r) {
                const float t = __builtin_fmaf(-2.f, acc[m][r], ny);
                red[m][r] = (MODE == 0) ? fmaxf(red[m][r], t) : fminf(red[m][r], t);
            }
    }

    float na[4][4];
    #pragma unroll
    for (int m = 0; m < 4; ++m)
        #pragma unroll
        for (int r = 0; r < 4; ++r)
            na[m][r] = nA[(rt0 + m) * 16 + 4 * lk + r];

    if (MODE == 0) {
        #pragma unroll
        for (int msk = 1; msk < 16; msk <<= 1)
            #pragma unroll
            for (int m = 0; m < 4; ++m)
                #pragma unroll
                for (int r = 0; r < 4; ++r)
                    red[m][r] = fmaxf(red[m][r], __shfl_xor(red[m][r], msk));
        if (lm == 0) {
            #pragma unroll
            for (int m = 0; m < 4; ++m)
                #pragma unroll
                for (int r = 0; r < 4; ++r) {
                    const float sq = fmaxf(na[m][r] + red[m][r], 0.f);
                    atomicMax(dposBits + ((rt0 + m) * 16 + 4 * lk + r),
                              __float_as_uint(sq));
                }
        }
    } else {
        float mn = 3.4e38f;
        #pragma unroll
        for (int m = 0; m < 4; ++m)
            #pragma unroll
            for (int r = 0; r < 4; ++r)
                mn = fminf(mn, na[m][r] + red[m][r]);
        mn = fmaxf(mn, 0.f);
        #pragma unroll
        for (int msk = 1; msk < 64; msk <<= 1) mn = fminf(mn, __shfl_xor(mn, msk));
        __shared__ float wmin[4];
        if (lane == 0) wmin[wid] = mn;
        __syncthreads();
        if (threadIdx.x == 0) {
            const float m2 = fminf(fminf(wmin[0], wmin[1]), fminf(wmin[2], wmin[3]));
            atomicMin(dnegBits, __float_as_uint(m2));
        }
    }
}

#define POS_BLOCKS ((P_POS / 128) * (B_ANCH / 128))          // 256
#define NEG_CT 8
#define NEG_BLOCKS ((N_NEG / (128 * NEG_CT)) * (B_ANCH / 128)) // 512

__global__ __launch_bounds__(256, 2) void fused_dist_kernel(
    const short* __restrict__ pA, const short* __restrict__ pP,
    const short* __restrict__ pN,
    const float* __restrict__ nA, const float* __restrict__ nP,
    const float* __restrict__ nN,
    unsigned* __restrict__ dposBits, unsigned* __restrict__ dnegBits)
{
    const int bid = blockIdx.x;
    if (bid < POS_BLOCKS) {
        // positives: short blocks first so they co-schedule with negatives
        dist_tile<0, 1>((const bf16x8*)pA, (const bf16x8*)pP, nA, nP,
                        bid >> 4, bid & 15, dposBits, dnegBits);
    } else {
        const int q = bid - POS_BLOCKS;
        dist_tile<1, NEG_CT>((const bf16x8*)pA, (const bf16x8*)pN, nA, nN,
                             q >> 5, q & 31, dposBits, dnegBits);
    }
}

// ---------------------------------------------------------------------------
// Finalize: mean(relu(sqrt(dpos_sq) - sqrt(dneg_sq) + margin))
// ---------------------------------------------------------------------------
__global__ __launch_bounds__(256) void finalize_kernel(
    const unsigned* __restrict__ dposBits, const unsigned* __restrict__ dnegBits,
    float* __restrict__ out)
{
    const float dneg = sqrtf(__uint_as_float(*dnegBits));
    float s = 0.f;
    for (int i = threadIdx.x; i < B_ANCH; i += 256) {
        float dp = sqrtf(__uint_as_float(dposBits[i]));
        s += fmaxf(dp - dneg + MARGIN_F, 0.f);
    }
    #pragma unroll
    for (int m = 1; m < 64; m <<= 1) s += __shfl_xor(s, m);
    __shared__ float ws[4];
    const int wid = threadIdx.x >> 6, lane = threadIdx.x & 63;
    if (lane == 0) ws[wid] = s;
    __syncthreads();
    if (threadIdx.x == 0)
        out[0] = (ws[0] + ws[1] + ws[2] + ws[3]) * (1.f / (float)B_ANCH);
}

// ---------------------------------------------------------------------------
extern "C" void kernel_launch(void* const* d_in, const int* in_sizes, int n_in,
                              void* d_out, int out_size, void* d_ws, size_t ws_size,
                              hipStream_t stream) {
    const float* anchor   = (const float*)d_in[0];
    const float* positive = (const float*)d_in[1];
    const float* negative = (const float*)d_in[2];
    float* out = (float*)d_out;

    char* ws = (char*)d_ws;
    size_t off = 0;
    auto alloc = [&](size_t bytes) { char* p = ws + off; off = (off + bytes + 255) & ~(size_t)255; return p; };

    short* pA = (short*)alloc((size_t)B_ANCH * DDIM * 2);
    short* pP = (short*)alloc((size_t)P_POS  * DDIM * 2);
    short* pN = (short*)alloc((size_t)N_NEG  * DDIM * 2);
    float* nA  = (float*)alloc((size_t)B_ANCH * 4);
    float* nP  = (float*)alloc((size_t)P_POS  * 4);
    float* nN  = (float*)alloc((size_t)N_NEG  * 4);
    unsigned* dposBits = (unsigned*)alloc((size_t)B_ANCH * 4);
    unsigned* dnegBits = (unsigned*)alloc(4);

    // 1. prep: one wave per 16-row tile, 4 tiles per block
    const int totalTiles = (B_ANCH + P_POS + N_NEG) / 16;   // 2304
    prep_kernel<<<totalTiles / 4, 256, 0, stream>>>(
        anchor, positive, negative, pA, pP, pN, nA, nP, nN, dposBits, dnegBits);

    // 2. fused positives + negatives distance/reduce
    fused_dist_kernel<<<POS_BLOCKS + NEG_BLOCKS, 256, 0, stream>>>(
        pA, pP, pN, nA, nP, nN, dposBits, dnegBits);

    // 3. finalize
    finalize_kernel<<<1, 256, 0, stream>>>(dposBits, dnegBits, out);
}